// Round 11
// baseline (142.047 us; speedup 1.0000x reference)
//
#include <hip/hip_runtime.h>
#include <cstdint>

// StreamNet K3 S1 halo conv, bf16 MFMA implicit-GEMM.
// R16: two-round scheduling. Model after R6..R15: duration = reads/r + tail,
// r pinned ~2.6 TB/s at 4 blk/CU (occupancy/width/depth/pipelining all
// probed); with grid 1024 = exactly 4 blocks/CU there is ONE round, so the
// final compute tails hide under nothing. R16: grid 2048, one 16x16 tile
// per block -> TWO rounds/CU; round-2 blocks' load bursts overlap round-1
// blocks' tails. Per-block tail halves (single sweep). Components all
// previously verified: R13's sweep economics (A-frags read once, Bf[9][2]
// persistent in regs, direct-from-global = L1-hot), R15's 16x16 staging +
// halo geometry, single barrier, plain (256,2) (R7/R10/R11: min-occupancy
// attrs >=3 => RA squeeze + spill; never again), Bf loaded after stage
// stores to keep peak live set ~120 <= 128 (4 waves/EU preserved).
// LDS 20736B; XCD swizzle: batch i -> XCD i.
//
// Padded input Xp[b][c][r][cc], r,cc in [0,258):
//   r < 2           -> bbuf[b][c][r][cc]           (bbuf [B][C][2][258])
//   r>=2, cc < 2    -> rbuf[b][c][r-2][cc]         (rbuf [B][C][256][2])
//   r>=2, cc>=2     -> (cc-2 == 255) ? 0 : x[b][c][r-2][cc-2]

constexpr int B  = 8;
constexpr int C  = 32;
constexpr int P  = 256;
constexpr int KB = 2;
constexpr int TS = 16;            // tile side
constexpr int RS = 18;            // LDS row stride (dwords) == padded width
constexpr int PL = 324;           // plane stride (dwords); 4q*324 %32 = {0,16} -> 2-way, free
constexpr int XSZ = 16 * PL;      // 5184 dwords = 20736 B

typedef short bf16x8 __attribute__((ext_vector_type(8)));
typedef float f32x4  __attribute__((ext_vector_type(4)));
union Frag { uint32_t u[4]; bf16x8 v; };

static __device__ __forceinline__ uint32_t pk_bf16(float lo, float hi) {
    uint32_t a  = __builtin_bit_cast(uint32_t, lo);
    uint32_t b2 = __builtin_bit_cast(uint32_t, hi);
    a  += 0x7FFFu + ((a  >> 16) & 1u);
    b2 += 0x7FFFu + ((b2 >> 16) & 1u);
    return (a >> 16) | (b2 & 0xFFFF0000u);
}

// ---- prologue: pack W [C][C][3][3] f32 -> bf16-pair image in d_ws ----
// image dword index: t*512 + oc*16 + icpair, halves (lo,hi) = ic (2m, 2m+1)
__global__ __launch_bounds__(256) void pack_w_kernel(
    const float* __restrict__ W, uint32_t* __restrict__ wpk)
{
    const int g = blockIdx.x * 256 + threadIdx.x;      // 0..2303
    const float4 v = ((const float4*)W)[g];
    const float vv[4] = { v.x, v.y, v.z, v.w };
    uint16_t* wh = (uint16_t*)wpk;
    #pragma unroll
    for (int e = 0; e < 4; ++e) {
        const int flat = 4 * g + e;                    // (oc*32+ic)*9 + t
        const int t    = flat % 9;
        const int rest = flat / 9;
        const int ic   = rest & 31;
        const int oc   = rest >> 5;
        const uint32_t u = __builtin_bit_cast(uint32_t, vv[e]);
        const uint16_t h = (uint16_t)((u + 0x7FFFu + ((u >> 16) & 1u)) >> 16);
        wh[(t * 512 + oc * 16 + (ic >> 1)) * 2 + (ic & 1)] = h;
    }
}

struct St16 {                      // one plane-pair's staged data (16x16 tile)
    float4 a0, c0;                 // interior: lo plane, hi plane (4 cols/lane)
    float  h0l, h0h, h1l, h1h;     // 2 halo cells x (lo, hi)
};

__global__ __launch_bounds__(256, 2) void conv_mfma(
    const float* __restrict__ x,      // [B][C][P][P]
    const float* __restrict__ rbuf,   // [B][C][P][KB]
    const float* __restrict__ bbuf,   // [B][C][KB][P+KB]
    const uint32_t* __restrict__ wpk, // packed W image (4608 dwords, fits L1)
    const float* __restrict__ bias,   // [C]
    float* __restrict__ out)          // [B][C][P][P]
{
    const int tid  = threadIdx.x;
    const int lane = tid & 63;
    const int w    = tid >> 6;        // wave 0..3
    const int q    = lane >> 4;
    const int n16  = lane & 15;

    // XCD swizzle: 2048 blocks round-robin -> XCD i gets sw [256i,256(i+1))
    // = all 256 tiles of batch i (in-XCD halo/L2 reuse).
    const int sw = (blockIdx.x & 7) * 256 + (blockIdx.x >> 3);
    const int b  = sw >> 8;
    const int ty = (sw >> 4) & 15;
    const int cx = sw & 15;
    const int x0 = cx * TS, y0 = ty * TS;

    __shared__ uint32_t Xs[XSZ];

    // ---- staging lane geometry (16x16) ----
    const int srow = lane >> 2;                 // 0..15
    const int scol = (lane & 3) * 4;            // 0,4,8,12
    const bool zc  = (cx == 15) && ((lane & 3) == 3);   // col 255 in .w

    // halo cells: 68 = top 2x18 (c 0..35) + left 16x2 (c 36..67)
    int h_ldso[2], h_ps[2];
    const float* h_bp[2];
    bool h_z[2];
    {
        const float* xb0 = x    + (size_t)b * C * P * P;
        const float* rb0 = rbuf + (size_t)b * C * P * KB;
        const float* bb0 = bbuf + (size_t)b * C * KB * (P + KB);
        const float* basep[3] = { xb0, rb0, bb0 };
        const int    psz[3]   = { P * P, P * KB, KB * (P + KB) };
        #pragma unroll
        for (int ci = 0; ci < 2; ++ci) {
            const int c = lane + 64 * ci;
            int prow, pcol;
            if (c < 36) { const int hr = (c >= 18) ? 1 : 0; prow = hr; pcol = c - 18 * hr; }
            else        { const int cc = c - 36; prow = KB + (cc >> 1); pcol = cc & 1; }
            h_ldso[ci] = prow * RS + pcol;
            const int gr = y0 + prow, gc = x0 + pcol;
            int sel, off; bool z = false;
            if (gr < KB)      { sel = 2; off = gr * (P + KB) + gc; }
            else if (gc < KB) { sel = 1; off = (gr - KB) * KB + gc; }
            else              { sel = 0; off = (gr - KB) * P + (gc - KB);
                                z = (gc == P + KB - 1); }
            h_bp[ci] = basep[sel] + off;
            h_ps[ci] = psz[sel];
            h_z[ci]  = z;
        }
    }
    const bool h1a = lane < 4;                  // cell1 active

    const float* xb = x + (size_t)b * C * P * P;

    // ---- 1. issue ALL X loads (deep queue) ----
    St16 S[4];
    #pragma unroll
    for (int k2 = 0; k2 < 4; ++k2) {
        const int m = 4 * k2 + w;
        const float* pi = xb + (size_t)(2 * m) * (P * P) + (y0 + srow) * P + x0 + scol;
        S[k2].a0 = *(const float4*)pi;
        S[k2].c0 = *(const float4*)(pi + P * P);
        const float* p0 = h_bp[0] + (size_t)(2 * m) * h_ps[0];
        S[k2].h0l = h_z[0] ? 0.f : p0[0];
        S[k2].h0h = h_z[0] ? 0.f : p0[h_ps[0]];
        if (h1a) {
            const float* p1 = h_bp[1] + (size_t)(2 * m) * h_ps[1];
            S[k2].h1l = h_z[1] ? 0.f : p1[0];
            S[k2].h1h = h_z[1] ? 0.f : p1[h_ps[1]];
        }
    }

    // ---- 2. pack + store X tiles to LDS (b64 stores) ----
    #pragma unroll
    for (int k2 = 0; k2 < 4; ++k2) {
        const int m = 4 * k2 + w;
        float4 a0 = S[k2].a0, c0 = S[k2].c0;
        if (zc) { a0.w = 0.f; c0.w = 0.f; }
        uint2 p0, p1;
        p0.x = pk_bf16(a0.x, c0.x); p0.y = pk_bf16(a0.y, c0.y);
        p1.x = pk_bf16(a0.z, c0.z); p1.y = pk_bf16(a0.w, c0.w);
        uint32_t* base = Xs + m * PL + (srow + KB) * RS + KB + scol;  // 8B aligned
        *(uint2*)(base + 0) = p0;
        *(uint2*)(base + 2) = p1;
        Xs[m * PL + h_ldso[0]] = pk_bf16(S[k2].h0l, S[k2].h0h);
        if (h1a) Xs[m * PL + h_ldso[1]] = pk_bf16(S[k2].h1l, S[k2].h1h);
    }

    // ---- 3. Bf fragments DIRECT from global W image (L1-hot, 16B/lane) ----
    Frag Bf[9][2];
    #pragma unroll
    for (int t = 0; t < 9; ++t)
        #pragma unroll
        for (int oh = 0; oh < 2; ++oh)
            *(uint4*)Bf[t][oh].u =
                *(const uint4*)&wpk[t * 512 + (oh * 16 + n16) * 16 + q * 4];
    const float bv0 = bias[n16];
    const float bv1 = bias[16 + n16];

    __syncthreads();   // single barrier: staged tile visible to all waves

    // ---- 4. MFMA sweep (A-frags read once, serve both oh) ----
    f32x4 acc[4][2];
    #pragma unroll
    for (int rr = 0; rr < 4; ++rr)
        #pragma unroll
        for (int oh = 0; oh < 2; ++oh)
            #pragma unroll
            for (int e = 0; e < 4; ++e) acc[rr][oh][e] = 0.f;

    // A-frags deduped: padded row 4w+dr serves all (rr,ky) with rr+ky==dr
    #pragma unroll
    for (int dr = 0; dr < 6; ++dr) {
        Frag A[3];
        const uint32_t* ap = Xs + (4 * q) * PL + (4 * w + dr) * RS + n16;
        #pragma unroll
        for (int kx = 0; kx < 3; ++kx)
            #pragma unroll
            for (int p = 0; p < 4; ++p)
                A[kx].u[p] = ap[p * PL + kx];
        #pragma unroll
        for (int ky = 0; ky < 3; ++ky) {
            const int rr = dr - ky;
            if (rr >= 0 && rr < 4) {
                #pragma unroll
                for (int kx = 0; kx < 3; ++kx) {
                    acc[rr][0] = __builtin_amdgcn_mfma_f32_16x16x32_bf16(
                                     A[kx].v, Bf[ky * 3 + kx][0].v, acc[rr][0], 0, 0, 0);
                    acc[rr][1] = __builtin_amdgcn_mfma_f32_16x16x32_bf16(
                                     A[kx].v, Bf[ky * 3 + kx][1].v, acc[rr][1], 0, 0, 0);
                }
            }
        }
    }

    // ---- 5. epilogue: plain float4 stores ----
    #pragma unroll
    for (int oh = 0; oh < 2; ++oh) {
        const int oc = oh * 16 + n16;
        const float bv = oh ? bv1 : bv0;
        #pragma unroll
        for (int rr = 0; rr < 4; ++rr) {
            float4 v;
            v.x = acc[rr][oh][0] + bv;
            v.y = acc[rr][oh][1] + bv;
            v.z = acc[rr][oh][2] + bv;
            v.w = acc[rr][oh][3] + bv;
            *(float4*)&out[((size_t)(b * C + oc) * P + (y0 + 4 * w + rr)) * P
                           + x0 + 4 * q] = v;
        }
    }
}

extern "C" void kernel_launch(void* const* d_in, const int* in_sizes, int n_in,
                              void* d_out, int out_size, void* d_ws, size_t ws_size,
                              hipStream_t stream) {
    const float* x    = (const float*)d_in[0];
    const float* rbuf = (const float*)d_in[1];
    const float* bbuf = (const float*)d_in[2];
    const float* W    = (const float*)d_in[3];
    const float* bias = (const float*)d_in[4];
    float* out = (float*)d_out;
    uint32_t* wpk = (uint32_t*)d_ws;              // 18432 B used

    pack_w_kernel<<<9, 256, 0, stream>>>(W, wpk);
    conv_mfma<<<2048, 256, 0, stream>>>(x, rbuf, bbuf, wpk, bias, out);
}

// Round 12
// 139.717 us; speedup vs baseline: 1.0167x; 1.0167x over previous
//
#include <hip/hip_runtime.h>
#include <cstdint>

// StreamNet K3 S1 halo conv, bf16 MFMA implicit-GEMM.
// R17 = R16 + LDS padded to 39424B. R16 finding (4th RA-squeeze incident):
// small LDS (21KB -> 7 blk/CU headroom) makes the RA squeeze VGPRs to 68 —
// below Bf[9][2]'s 72 — spilling INTO the MFMA loop (WRITE +4MB, scratch
// reloads on the sweep critical path). The squeeze trigger is anything that
// raises theoretical blocks/CU: min-occupancy attrs (R7/R10/R11) OR small
// LDS (R16). R12/R13's 39.4KB LDS was load-bearing: it caps blocks/CU at 4,
// pinning the RA target at 4 waves/EU = 128 regs. R17 pads Xs to 9856 dw
// (uses first 5184) to restore that pin while keeping R16's grid 2048 =
// one 16x16 tile per block -> TWO scheduling rounds per CU: round-2 load
// bursts launch under round-1 compute tails (the tail-overlap experiment
// R16 was meant to run, now without spill). Per-block tail = half of R13's.
// Keeps: R13 sweep economics (A-frags read once, Bf[9][2] persistent,
// direct-from-global = L1-hot), pack_w prologue, single barrier, plain
// (256,2), Bf loaded after stage stores, XCD swizzle (batch i -> XCD i),
// plain f4 epilogue stores.
//
// Padded input Xp[b][c][r][cc], r,cc in [0,258):
//   r < 2           -> bbuf[b][c][r][cc]           (bbuf [B][C][2][258])
//   r>=2, cc < 2    -> rbuf[b][c][r-2][cc]         (rbuf [B][C][256][2])
//   r>=2, cc>=2     -> (cc-2 == 255) ? 0 : x[b][c][r-2][cc-2]

constexpr int B  = 8;
constexpr int C  = 32;
constexpr int P  = 256;
constexpr int KB = 2;
constexpr int TS = 16;            // tile side
constexpr int RS = 18;            // LDS row stride (dwords) == padded width
constexpr int PL = 324;           // plane stride (dwords); 4q*324 %32 = {0,16} -> 2-way, free
constexpr int XSZ = 16 * PL;      // 5184 dwords used
constexpr int LDSZ = 9856;        // padded to 39424B: pins RA occupancy target
                                  // at 4 blk/CU -> 128-reg budget (anti-squeeze)

typedef short bf16x8 __attribute__((ext_vector_type(8)));
typedef float f32x4  __attribute__((ext_vector_type(4)));
union Frag { uint32_t u[4]; bf16x8 v; };

static __device__ __forceinline__ uint32_t pk_bf16(float lo, float hi) {
    uint32_t a  = __builtin_bit_cast(uint32_t, lo);
    uint32_t b2 = __builtin_bit_cast(uint32_t, hi);
    a  += 0x7FFFu + ((a  >> 16) & 1u);
    b2 += 0x7FFFu + ((b2 >> 16) & 1u);
    return (a >> 16) | (b2 & 0xFFFF0000u);
}

// ---- prologue: pack W [C][C][3][3] f32 -> bf16-pair image in d_ws ----
// image dword index: t*512 + oc*16 + icpair, halves (lo,hi) = ic (2m, 2m+1)
__global__ __launch_bounds__(256) void pack_w_kernel(
    const float* __restrict__ W, uint32_t* __restrict__ wpk)
{
    const int g = blockIdx.x * 256 + threadIdx.x;      // 0..2303
    const float4 v = ((const float4*)W)[g];
    const float vv[4] = { v.x, v.y, v.z, v.w };
    uint16_t* wh = (uint16_t*)wpk;
    #pragma unroll
    for (int e = 0; e < 4; ++e) {
        const int flat = 4 * g + e;                    // (oc*32+ic)*9 + t
        const int t    = flat % 9;
        const int rest = flat / 9;
        const int ic   = rest & 31;
        const int oc   = rest >> 5;
        const uint32_t u = __builtin_bit_cast(uint32_t, vv[e]);
        const uint16_t h = (uint16_t)((u + 0x7FFFu + ((u >> 16) & 1u)) >> 16);
        wh[(t * 512 + oc * 16 + (ic >> 1)) * 2 + (ic & 1)] = h;
    }
}

struct St16 {                      // one plane-pair's staged data (16x16 tile)
    float4 a0, c0;                 // interior: lo plane, hi plane (4 cols/lane)
    float  h0l, h0h, h1l, h1h;     // 2 halo cells x (lo, hi)
};

__global__ __launch_bounds__(256, 2) void conv_mfma(
    const float* __restrict__ x,      // [B][C][P][P]
    const float* __restrict__ rbuf,   // [B][C][P][KB]
    const float* __restrict__ bbuf,   // [B][C][KB][P+KB]
    const uint32_t* __restrict__ wpk, // packed W image (4608 dwords, fits L1)
    const float* __restrict__ bias,   // [C]
    float* __restrict__ out)          // [B][C][P][P]
{
    const int tid  = threadIdx.x;
    const int lane = tid & 63;
    const int w    = tid >> 6;        // wave 0..3
    const int q    = lane >> 4;
    const int n16  = lane & 15;

    // XCD swizzle: 2048 blocks round-robin -> XCD i gets sw [256i,256(i+1))
    // = all 256 tiles of batch i (in-XCD halo/L2 reuse).
    const int sw = (blockIdx.x & 7) * 256 + (blockIdx.x >> 3);
    const int b  = sw >> 8;
    const int ty = (sw >> 4) & 15;
    const int cx = sw & 15;
    const int x0 = cx * TS, y0 = ty * TS;

    __shared__ uint32_t Xs[LDSZ];     // only [0,XSZ) used; rest = RA pin pad

    // ---- staging lane geometry (16x16) ----
    const int srow = lane >> 2;                 // 0..15
    const int scol = (lane & 3) * 4;            // 0,4,8,12
    const bool zc  = (cx == 15) && ((lane & 3) == 3);   // col 255 in .w

    // halo cells: 68 = top 2x18 (c 0..35) + left 16x2 (c 36..67)
    int h_ldso[2], h_ps[2];
    const float* h_bp[2];
    bool h_z[2];
    {
        const float* xb0 = x    + (size_t)b * C * P * P;
        const float* rb0 = rbuf + (size_t)b * C * P * KB;
        const float* bb0 = bbuf + (size_t)b * C * KB * (P + KB);
        const float* basep[3] = { xb0, rb0, bb0 };
        const int    psz[3]   = { P * P, P * KB, KB * (P + KB) };
        #pragma unroll
        for (int ci = 0; ci < 2; ++ci) {
            const int c = lane + 64 * ci;
            int prow, pcol;
            if (c < 36) { const int hr = (c >= 18) ? 1 : 0; prow = hr; pcol = c - 18 * hr; }
            else        { const int cc = c - 36; prow = KB + (cc >> 1); pcol = cc & 1; }
            h_ldso[ci] = prow * RS + pcol;
            const int gr = y0 + prow, gc = x0 + pcol;
            int sel, off; bool z = false;
            if (gr < KB)      { sel = 2; off = gr * (P + KB) + gc; }
            else if (gc < KB) { sel = 1; off = (gr - KB) * KB + gc; }
            else              { sel = 0; off = (gr - KB) * P + (gc - KB);
                                z = (gc == P + KB - 1); }
            h_bp[ci] = basep[sel] + off;
            h_ps[ci] = psz[sel];
            h_z[ci]  = z;
        }
    }
    const bool h1a = lane < 4;                  // cell1 active

    const float* xb = x + (size_t)b * C * P * P;

    // ---- 1. issue ALL X loads (deep queue) ----
    St16 S[4];
    #pragma unroll
    for (int k2 = 0; k2 < 4; ++k2) {
        const int m = 4 * k2 + w;
        const float* pi = xb + (size_t)(2 * m) * (P * P) + (y0 + srow) * P + x0 + scol;
        S[k2].a0 = *(const float4*)pi;
        S[k2].c0 = *(const float4*)(pi + P * P);
        const float* p0 = h_bp[0] + (size_t)(2 * m) * h_ps[0];
        S[k2].h0l = h_z[0] ? 0.f : p0[0];
        S[k2].h0h = h_z[0] ? 0.f : p0[h_ps[0]];
        if (h1a) {
            const float* p1 = h_bp[1] + (size_t)(2 * m) * h_ps[1];
            S[k2].h1l = h_z[1] ? 0.f : p1[0];
            S[k2].h1h = h_z[1] ? 0.f : p1[h_ps[1]];
        }
    }

    // ---- 2. pack + store X tiles to LDS (b64 stores) ----
    #pragma unroll
    for (int k2 = 0; k2 < 4; ++k2) {
        const int m = 4 * k2 + w;
        float4 a0 = S[k2].a0, c0 = S[k2].c0;
        if (zc) { a0.w = 0.f; c0.w = 0.f; }
        uint2 p0, p1;
        p0.x = pk_bf16(a0.x, c0.x); p0.y = pk_bf16(a0.y, c0.y);
        p1.x = pk_bf16(a0.z, c0.z); p1.y = pk_bf16(a0.w, c0.w);
        uint32_t* base = Xs + m * PL + (srow + KB) * RS + KB + scol;  // 8B aligned
        *(uint2*)(base + 0) = p0;
        *(uint2*)(base + 2) = p1;
        Xs[m * PL + h_ldso[0]] = pk_bf16(S[k2].h0l, S[k2].h0h);
        if (h1a) Xs[m * PL + h_ldso[1]] = pk_bf16(S[k2].h1l, S[k2].h1h);
    }

    // ---- 3. Bf fragments DIRECT from global W image (L1-hot, 16B/lane) ----
    Frag Bf[9][2];
    #pragma unroll
    for (int t = 0; t < 9; ++t)
        #pragma unroll
        for (int oh = 0; oh < 2; ++oh)
            *(uint4*)Bf[t][oh].u =
                *(const uint4*)&wpk[t * 512 + (oh * 16 + n16) * 16 + q * 4];
    const float bv0 = bias[n16];
    const float bv1 = bias[16 + n16];

    __syncthreads();   // single barrier: staged tile visible to all waves

    // ---- 4. MFMA sweep (A-frags read once, serve both oh) ----
    f32x4 acc[4][2];
    #pragma unroll
    for (int rr = 0; rr < 4; ++rr)
        #pragma unroll
        for (int oh = 0; oh < 2; ++oh)
            #pragma unroll
            for (int e = 0; e < 4; ++e) acc[rr][oh][e] = 0.f;

    // A-frags deduped: padded row 4w+dr serves all (rr,ky) with rr+ky==dr
    #pragma unroll
    for (int dr = 0; dr < 6; ++dr) {
        Frag A[3];
        const uint32_t* ap = Xs + (4 * q) * PL + (4 * w + dr) * RS + n16;
        #pragma unroll
        for (int kx = 0; kx < 3; ++kx)
            #pragma unroll
            for (int p = 0; p < 4; ++p)
                A[kx].u[p] = ap[p * PL + kx];
        #pragma unroll
        for (int ky = 0; ky < 3; ++ky) {
            const int rr = dr - ky;
            if (rr >= 0 && rr < 4) {
                #pragma unroll
                for (int kx = 0; kx < 3; ++kx) {
                    acc[rr][0] = __builtin_amdgcn_mfma_f32_16x16x32_bf16(
                                     A[kx].v, Bf[ky * 3 + kx][0].v, acc[rr][0], 0, 0, 0);
                    acc[rr][1] = __builtin_amdgcn_mfma_f32_16x16x32_bf16(
                                     A[kx].v, Bf[ky * 3 + kx][1].v, acc[rr][1], 0, 0, 0);
                }
            }
        }
    }

    // ---- 5. epilogue: plain float4 stores ----
    #pragma unroll
    for (int oh = 0; oh < 2; ++oh) {
        const int oc = oh * 16 + n16;
        const float bv = oh ? bv1 : bv0;
        #pragma unroll
        for (int rr = 0; rr < 4; ++rr) {
            float4 v;
            v.x = acc[rr][oh][0] + bv;
            v.y = acc[rr][oh][1] + bv;
            v.z = acc[rr][oh][2] + bv;
            v.w = acc[rr][oh][3] + bv;
            *(float4*)&out[((size_t)(b * C + oc) * P + (y0 + 4 * w + rr)) * P
                           + x0 + 4 * q] = v;
        }
    }
}

extern "C" void kernel_launch(void* const* d_in, const int* in_sizes, int n_in,
                              void* d_out, int out_size, void* d_ws, size_t ws_size,
                              hipStream_t stream) {
    const float* x    = (const float*)d_in[0];
    const float* rbuf = (const float*)d_in[1];
    const float* bbuf = (const float*)d_in[2];
    const float* W    = (const float*)d_in[3];
    const float* bias = (const float*)d_in[4];
    float* out = (float*)d_out;
    uint32_t* wpk = (uint32_t*)d_ws;              // 18432 B used

    pack_w_kernel<<<9, 256, 0, stream>>>(W, wpk);
    conv_mfma<<<2048, 256, 0, stream>>>(x, rbuf, bbuf, wpk, bias, out);
}

// Round 13
// 137.658 us; speedup vs baseline: 1.0319x; 1.0150x over previous
//
#include <hip/hip_runtime.h>
#include <cstdint>

// StreamNet K3 S1 halo conv, bf16 MFMA implicit-GEMM.
// R18 = R17 + anti-rematerialization fences on Bf. R17 falsified the "LDS
// pad pins the RA" theory: VGPR stayed 68 (< Bf's 72) with CLEAN traffic
// (WRITE 66.7MB, no scratch) -> the RA wasn't scratch-spilling, it was
// REMATERIALIZING the Bf global loads inside the MFMA sweep (legal: pure
// loads from __restrict__ read-only memory). Zero cost in the RA's model,
// but vmcnt waits land on the sweep critical path -> 50us vs R13's 41.
// R13 escaped only because its 16x32 staging live-set (64 regs) forced the
// RA past the remat-attractive region. Fix: empty asm("" : "+v") on every
// Bf register after load -> value is no longer a pure load result -> must
// stay live (72 regs) or scratch-spill (rejected at budget 256).
// This finally runs the R16 two-round experiment unhandicapped: grid 2048,
// one 16x16 tile/block, 39424B LDS (4 blk/CU), round-2 blocks' load bursts
// overlap round-1 blocks' compute tails.
// Keeps: R13 sweep economics (A-frags read once, Bf[9][2] persistent,
// direct-from-global L1-hot), pack_w prologue, single barrier, plain
// (256,2) (R7/R10/R11: min-occupancy attrs >=3 = squeeze+spill), Bf loaded
// after stage stores, XCD swizzle (batch i -> XCD i), plain f4 stores.
//
// Padded input Xp[b][c][r][cc], r,cc in [0,258):
//   r < 2           -> bbuf[b][c][r][cc]           (bbuf [B][C][2][258])
//   r>=2, cc < 2    -> rbuf[b][c][r-2][cc]         (rbuf [B][C][256][2])
//   r>=2, cc>=2     -> (cc-2 == 255) ? 0 : x[b][c][r-2][cc-2]

constexpr int B  = 8;
constexpr int C  = 32;
constexpr int P  = 256;
constexpr int KB = 2;
constexpr int TS = 16;            // tile side
constexpr int RS = 18;            // LDS row stride (dwords) == padded width
constexpr int PL = 324;           // plane stride (dwords); 4q*324 %32 = {0,16} -> 2-way, free
constexpr int XSZ = 16 * PL;      // 5184 dwords used
constexpr int LDSZ = 9856;        // 39424B: 4 blk/CU (kept from R17)

typedef short bf16x8 __attribute__((ext_vector_type(8)));
typedef float f32x4  __attribute__((ext_vector_type(4)));
union Frag { uint32_t u[4]; bf16x8 v; };

static __device__ __forceinline__ uint32_t pk_bf16(float lo, float hi) {
    uint32_t a  = __builtin_bit_cast(uint32_t, lo);
    uint32_t b2 = __builtin_bit_cast(uint32_t, hi);
    a  += 0x7FFFu + ((a  >> 16) & 1u);
    b2 += 0x7FFFu + ((b2 >> 16) & 1u);
    return (a >> 16) | (b2 & 0xFFFF0000u);
}

// ---- prologue: pack W [C][C][3][3] f32 -> bf16-pair image in d_ws ----
// image dword index: t*512 + oc*16 + icpair, halves (lo,hi) = ic (2m, 2m+1)
__global__ __launch_bounds__(256) void pack_w_kernel(
    const float* __restrict__ W, uint32_t* __restrict__ wpk)
{
    const int g = blockIdx.x * 256 + threadIdx.x;      // 0..2303
    const float4 v = ((const float4*)W)[g];
    const float vv[4] = { v.x, v.y, v.z, v.w };
    uint16_t* wh = (uint16_t*)wpk;
    #pragma unroll
    for (int e = 0; e < 4; ++e) {
        const int flat = 4 * g + e;                    // (oc*32+ic)*9 + t
        const int t    = flat % 9;
        const int rest = flat / 9;
        const int ic   = rest & 31;
        const int oc   = rest >> 5;
        const uint32_t u = __builtin_bit_cast(uint32_t, vv[e]);
        const uint16_t h = (uint16_t)((u + 0x7FFFu + ((u >> 16) & 1u)) >> 16);
        wh[(t * 512 + oc * 16 + (ic >> 1)) * 2 + (ic & 1)] = h;
    }
}

struct St16 {                      // one plane-pair's staged data (16x16 tile)
    float4 a0, c0;                 // interior: lo plane, hi plane (4 cols/lane)
    float  h0l, h0h, h1l, h1h;     // 2 halo cells x (lo, hi)
};

__global__ __launch_bounds__(256, 2) void conv_mfma(
    const float* __restrict__ x,      // [B][C][P][P]
    const float* __restrict__ rbuf,   // [B][C][P][KB]
    const float* __restrict__ bbuf,   // [B][C][KB][P+KB]
    const uint32_t* __restrict__ wpk, // packed W image (4608 dwords, fits L1)
    const float* __restrict__ bias,   // [C]
    float* __restrict__ out)          // [B][C][P][P]
{
    const int tid  = threadIdx.x;
    const int lane = tid & 63;
    const int w    = tid >> 6;        // wave 0..3
    const int q    = lane >> 4;
    const int n16  = lane & 15;

    // XCD swizzle: 2048 blocks round-robin -> XCD i gets sw [256i,256(i+1))
    // = all 256 tiles of batch i (in-XCD halo/L2 reuse).
    const int sw = (blockIdx.x & 7) * 256 + (blockIdx.x >> 3);
    const int b  = sw >> 8;
    const int ty = (sw >> 4) & 15;
    const int cx = sw & 15;
    const int x0 = cx * TS, y0 = ty * TS;

    __shared__ uint32_t Xs[LDSZ];     // only [0,XSZ) used

    // ---- staging lane geometry (16x16) ----
    const int srow = lane >> 2;                 // 0..15
    const int scol = (lane & 3) * 4;            // 0,4,8,12
    const bool zc  = (cx == 15) && ((lane & 3) == 3);   // col 255 in .w

    // halo cells: 68 = top 2x18 (c 0..35) + left 16x2 (c 36..67)
    int h_ldso[2], h_ps[2];
    const float* h_bp[2];
    bool h_z[2];
    {
        const float* xb0 = x    + (size_t)b * C * P * P;
        const float* rb0 = rbuf + (size_t)b * C * P * KB;
        const float* bb0 = bbuf + (size_t)b * C * KB * (P + KB);
        const float* basep[3] = { xb0, rb0, bb0 };
        const int    psz[3]   = { P * P, P * KB, KB * (P + KB) };
        #pragma unroll
        for (int ci = 0; ci < 2; ++ci) {
            const int c = lane + 64 * ci;
            int prow, pcol;
            if (c < 36) { const int hr = (c >= 18) ? 1 : 0; prow = hr; pcol = c - 18 * hr; }
            else        { const int cc = c - 36; prow = KB + (cc >> 1); pcol = cc & 1; }
            h_ldso[ci] = prow * RS + pcol;
            const int gr = y0 + prow, gc = x0 + pcol;
            int sel, off; bool z = false;
            if (gr < KB)      { sel = 2; off = gr * (P + KB) + gc; }
            else if (gc < KB) { sel = 1; off = (gr - KB) * KB + gc; }
            else              { sel = 0; off = (gr - KB) * P + (gc - KB);
                                z = (gc == P + KB - 1); }
            h_bp[ci] = basep[sel] + off;
            h_ps[ci] = psz[sel];
            h_z[ci]  = z;
        }
    }
    const bool h1a = lane < 4;                  // cell1 active

    const float* xb = x + (size_t)b * C * P * P;

    // ---- 1. issue ALL X loads (deep queue) ----
    St16 S[4];
    #pragma unroll
    for (int k2 = 0; k2 < 4; ++k2) {
        const int m = 4 * k2 + w;
        const float* pi = xb + (size_t)(2 * m) * (P * P) + (y0 + srow) * P + x0 + scol;
        S[k2].a0 = *(const float4*)pi;
        S[k2].c0 = *(const float4*)(pi + P * P);
        const float* p0 = h_bp[0] + (size_t)(2 * m) * h_ps[0];
        S[k2].h0l = h_z[0] ? 0.f : p0[0];
        S[k2].h0h = h_z[0] ? 0.f : p0[h_ps[0]];
        if (h1a) {
            const float* p1 = h_bp[1] + (size_t)(2 * m) * h_ps[1];
            S[k2].h1l = h_z[1] ? 0.f : p1[0];
            S[k2].h1h = h_z[1] ? 0.f : p1[h_ps[1]];
        }
    }

    // ---- 2. pack + store X tiles to LDS (b64 stores) ----
    #pragma unroll
    for (int k2 = 0; k2 < 4; ++k2) {
        const int m = 4 * k2 + w;
        float4 a0 = S[k2].a0, c0 = S[k2].c0;
        if (zc) { a0.w = 0.f; c0.w = 0.f; }
        uint2 p0, p1;
        p0.x = pk_bf16(a0.x, c0.x); p0.y = pk_bf16(a0.y, c0.y);
        p1.x = pk_bf16(a0.z, c0.z); p1.y = pk_bf16(a0.w, c0.w);
        uint32_t* base = Xs + m * PL + (srow + KB) * RS + KB + scol;  // 8B aligned
        *(uint2*)(base + 0) = p0;
        *(uint2*)(base + 2) = p1;
        Xs[m * PL + h_ldso[0]] = pk_bf16(S[k2].h0l, S[k2].h0h);
        if (h1a) Xs[m * PL + h_ldso[1]] = pk_bf16(S[k2].h1l, S[k2].h1h);
    }

    // ---- 3. Bf fragments DIRECT from global W image (L1-hot, 16B/lane),
    //         then anti-remat fence: value no longer a pure load result,
    //         so the RA must keep all 72 regs live through the sweep
    //         instead of re-issuing global loads inside it (R17 bug). ----
    Frag Bf[9][2];
    #pragma unroll
    for (int t = 0; t < 9; ++t)
        #pragma unroll
        for (int oh = 0; oh < 2; ++oh)
            *(uint4*)Bf[t][oh].u =
                *(const uint4*)&wpk[t * 512 + (oh * 16 + n16) * 16 + q * 4];
    #pragma unroll
    for (int t = 0; t < 9; ++t)
        #pragma unroll
        for (int oh = 0; oh < 2; ++oh)
            #pragma unroll
            for (int p = 0; p < 4; ++p)
                asm volatile("" : "+v"(Bf[t][oh].u[p]));
    const float bv0 = bias[n16];
    const float bv1 = bias[16 + n16];

    __syncthreads();   // single barrier: staged tile visible to all waves

    // ---- 4. MFMA sweep (A-frags read once, serve both oh) ----
    f32x4 acc[4][2];
    #pragma unroll
    for (int rr = 0; rr < 4; ++rr)
        #pragma unroll
        for (int oh = 0; oh < 2; ++oh)
            #pragma unroll
            for (int e = 0; e < 4; ++e) acc[rr][oh][e] = 0.f;

    // A-frags deduped: padded row 4w+dr serves all (rr,ky) with rr+ky==dr
    #pragma unroll
    for (int dr = 0; dr < 6; ++dr) {
        Frag A[3];
        const uint32_t* ap = Xs + (4 * q) * PL + (4 * w + dr) * RS + n16;
        #pragma unroll
        for (int kx = 0; kx < 3; ++kx)
            #pragma unroll
            for (int p = 0; p < 4; ++p)
                A[kx].u[p] = ap[p * PL + kx];
        #pragma unroll
        for (int ky = 0; ky < 3; ++ky) {
            const int rr = dr - ky;
            if (rr >= 0 && rr < 4) {
                #pragma unroll
                for (int kx = 0; kx < 3; ++kx) {
                    acc[rr][0] = __builtin_amdgcn_mfma_f32_16x16x32_bf16(
                                     A[kx].v, Bf[ky * 3 + kx][0].v, acc[rr][0], 0, 0, 0);
                    acc[rr][1] = __builtin_amdgcn_mfma_f32_16x16x32_bf16(
                                     A[kx].v, Bf[ky * 3 + kx][1].v, acc[rr][1], 0, 0, 0);
                }
            }
        }
    }

    // ---- 5. epilogue: plain float4 stores ----
    #pragma unroll
    for (int oh = 0; oh < 2; ++oh) {
        const int oc = oh * 16 + n16;
        const float bv = oh ? bv1 : bv0;
        #pragma unroll
        for (int rr = 0; rr < 4; ++rr) {
            float4 v;
            v.x = acc[rr][oh][0] + bv;
            v.y = acc[rr][oh][1] + bv;
            v.z = acc[rr][oh][2] + bv;
            v.w = acc[rr][oh][3] + bv;
            *(float4*)&out[((size_t)(b * C + oc) * P + (y0 + 4 * w + rr)) * P
                           + x0 + 4 * q] = v;
        }
    }
}

extern "C" void kernel_launch(void* const* d_in, const int* in_sizes, int n_in,
                              void* d_out, int out_size, void* d_ws, size_t ws_size,
                              hipStream_t stream) {
    const float* x    = (const float*)d_in[0];
    const float* rbuf = (const float*)d_in[1];
    const float* bbuf = (const float*)d_in[2];
    const float* W    = (const float*)d_in[3];
    const float* bias = (const float*)d_in[4];
    float* out = (float*)d_out;
    uint32_t* wpk = (uint32_t*)d_ws;              // 18432 B used

    pack_w_kernel<<<9, 256, 0, stream>>>(W, wpk);
    conv_mfma<<<2048, 256, 0, stream>>>(x, rbuf, bbuf, wpk, bias, out);
}